// Round 15
// baseline (417.221 us; speedup 1.0000x reference)
//
#include <hip/hip_runtime.h>
#include <hip/hip_cooperative_groups.h>

namespace cg = cooperative_groups;

#define CIN   512
#define COUT  256
#define HWDIM 32
#define NBATCH 64
#define PIX_PER_IMG (HWDIM * HWDIM)          // 1024
#define NPIX (NBATCH * PIX_PER_IMG)          // 65536

typedef __attribute__((ext_vector_type(4))) int   i32x4;
typedef __attribute__((ext_vector_type(8))) int   i32x8;
typedef __attribute__((ext_vector_type(4))) float f32x4;

// ---------------- workspace layout ----------------
// xb4 : [65536 pixels][256 B] fp4 signs NHWC     16,777,216 B @ 0
// wb4 : [9][256][256 B]       fp4 signs             589,824 B @ 16,777,216
// cv  : [64][256][1024] int16 (fallback path)    33,554,432 B @ 17,367,040
// psum: [256][1024] i32 (channel-major)           1,048,576 B @ 50,921,472
// psq : [256][1024] i64 (channel-major)           2,097,152 B @ 51,970,048
// scale/shift/zero page                                3 KB @ 54,067,200
#define OFF_XB4   ((size_t)0)
#define OFF_WB4   ((size_t)16777216)
#define OFF_CONV  ((size_t)17367040)
#define OFF_PSUM  ((size_t)50921472)
#define OFF_PSQ   ((size_t)51970048)
#define OFF_SCALE ((size_t)54067200)
#define OFF_SHIFT (OFF_SCALE + 1024)
#define OFF_ZERO  (OFF_SHIFT + 1024)         // 1024 B zero page (fp4 0x00 = +0.0)

// fp4 e2m1: +1.0 = 0x2, -1.0 = 0xA
#define NIB(v) ((v) >= 0.f ? 0x2u : 0xAu)

// ---------------- pack x: f32 NCHW -> fp4 sign NHWC ----------------
__global__ __launch_bounds__(256) void pack_x4_kernel(const float* __restrict__ x,
                                                      unsigned char* __restrict__ xb4) {
  const int plane = blockIdx.x;            // n*32 + h, 2048 planes
  const int n = plane >> 5, h = plane & 31;
  __shared__ unsigned int tile[HWDIM * 66];   // [w][66] words of 8 ci-nibbles
  const int t = threadIdx.x;
  const float* xp = x + (size_t)n * CIN * PIX_PER_IMG + (size_t)h * HWDIM;
#pragma unroll
  for (int it = 0; it < 2; ++it) {
    int idx = it * 256 + t;                // 0..511
    int cib = idx >> 3;                    // 8-ci group 0..63
    int w4 = (idx & 7) << 2;               // 0,4,..,28
    unsigned n0 = 0, n1 = 0, n2 = 0, n3 = 0;
#pragma unroll
    for (int d = 0; d < 8; ++d) {
      float4 f = *reinterpret_cast<const float4*>(
          xp + (size_t)(cib * 8 + d) * PIX_PER_IMG + w4);
      n0 |= NIB(f.x) << (4 * d);
      n1 |= NIB(f.y) << (4 * d);
      n2 |= NIB(f.z) << (4 * d);
      n3 |= NIB(f.w) << (4 * d);
    }
    tile[(w4 + 0) * 66 + cib] = n0;
    tile[(w4 + 1) * 66 + cib] = n1;
    tile[(w4 + 2) * 66 + cib] = n2;
    tile[(w4 + 3) * 66 + cib] = n3;
  }
  __syncthreads();
  uint4* xo = reinterpret_cast<uint4*>(xb4 + (size_t)plane * (HWDIM * CIN / 2));
#pragma unroll
  for (int it = 0; it < 2; ++it) {
    int cc = it * 256 + t;                 // 16B chunk 0..511
    int w = cc >> 4, c4 = (cc & 15) << 2;
    uint4 v = make_uint4(tile[w * 66 + c4], tile[w * 66 + c4 + 1],
                         tile[w * 66 + c4 + 2], tile[w * 66 + c4 + 3]);
    xo[cc] = v;
  }
}

// ---------------- pack W -> fp4 [tap][co][ci/2]; block 576 writes zero page ----
__global__ __launch_bounds__(256) void pack_w4_kernel(const float* __restrict__ W,
                                                      unsigned int* __restrict__ wb4,
                                                      unsigned int* __restrict__ zpw) {
  if (blockIdx.x == 576) {                  // 1 KB zero page for halo reads
    zpw[threadIdx.x] = 0u;
    return;
  }
  int idxu = blockIdx.x * 256 + threadIdx.x;    // u32 id, 9*256*64 = 147456 total
  int tap = idxu / (COUT * 64);
  int rem = idxu - tap * (COUT * 64);
  int co = rem >> 6;
  int ci0 = (rem & 63) << 3;
  unsigned nib = 0;
#pragma unroll
  for (int d = 0; d < 8; ++d) {
    float v = W[((size_t)co * CIN + ci0 + d) * 9 + tap];
    nib |= NIB(v) << (4 * d);
  }
  wb4[idxu] = nib;                          // layout [tap][co][64 words]
}

// ---------------- conv main loop (shared by fused + split kernels) ----------
#define BM 128
#define BKB 64                       // bytes per row per step (= 128 fp4 elems)
#define ABYTES (BM * BKB)            // 8192
#define BUFB   (ABYTES + COUT * BKB) // 24576
#define TAPB4 (COUT * (CIN / 2))     // 65536 B per tap of wb4

__device__ __forceinline__ void load16(const void* g, void* l) {
  __builtin_amdgcn_global_load_lds((const __attribute__((address_space(1))) void*)g,
                                   (__attribute__((address_space(3))) void*)l, 16, 0, 0);
}

__device__ __forceinline__ i32x8 up8(i32x4 v) {
  i32x8 r;
  r[0] = v[0]; r[1] = v[1]; r[2] = v[2]; r[3] = v[3];
  r[4] = 0;    r[5] = 0;    r[6] = 0;    r[7] = 0;
  return r;
}

__device__ __forceinline__ void conv_main(
    const unsigned char* __restrict__ xb4,
    const unsigned char* __restrict__ wb4,
    const unsigned char* __restrict__ zp,
    signed char (&lds)[2][BUFB],
    f32x4 (&acc)[4][4]) {
  const int t = threadIdx.x;
  const int lane = t & 63;
  const int wid = t >> 6;
  const int b = blockIdx.x;
  const int nimg = b >> 3;
  const int h0 = (b & 7) * 4;
  const int wr = wid >> 2;
  const int wc = wid & 3;

#pragma unroll
  for (int m = 0; m < 4; ++m)
#pragma unroll
    for (int n = 0; n < 4; ++n) { f32x4 z = {0.f, 0.f, 0.f, 0.f}; acc[m][n] = z; }

  auto abase = [&](int tap) -> const unsigned char* {
    int r = t >> 2;
    int sw = ((t & 3) ^ ((t >> 3) & 3)) << 4;
    int dh = tap / 3 - 1, dw = tap % 3 - 1;
    int hs = h0 + (r >> 5) + dh;
    int ws2 = (r & 31) + dw;
    bool ok = ((unsigned)hs < 32u) && ((unsigned)ws2 < 32u);
    return ok ? xb4 + (size_t)((nimg * 32 + hs) * 32 + ws2) * 256 + sw
              : zp + sw;
  };
  auto bbase = [&](int c) -> const unsigned char* {
    int co = c >> 2;
    int sw = ((c & 3) ^ ((c >> 3) & 3)) << 4;
    return wb4 + (size_t)co * 256 + sw;
  };

  const unsigned char* a0 = abase(0);
  const unsigned char* b0 = bbase(t);
  const unsigned char* b1 = bbase(512 + t);

  const int koff = (lane >> 4) << 4;
  const int ksw  = (((lane >> 1) & 3) << 4);
  int aoff[4], boff[4];
#pragma unroll
  for (int m = 0; m < 4; ++m) {
    int row = wr * 64 + m * 16 + (lane & 15);
    aoff[m] = row * BKB + (koff ^ ksw);
  }
#pragma unroll
  for (int n = 0; n < 4; ++n) {
    int col = wc * 64 + n * 16 + (lane & 15);
    boff[n] = ABYTES + col * BKB + (koff ^ ksw);
  }

  auto stage = [&](int buf, const unsigned char* A0, const unsigned char* B0,
                   const unsigned char* B1, int off) {
    signed char* dst = &lds[buf][0];
    load16(A0 + off, (void*)(dst + t * 16));
    load16(B0 + off, (void*)(dst + ABYTES + t * 16));
    load16(B1 + off, (void*)(dst + ABYTES + (512 + t) * 16));
  };

  auto compute = [&](int buf) {
    const signed char* base = &lds[buf][0];
    i32x4 af[4], bf[4];
#pragma unroll
    for (int n = 0; n < 4; ++n)
      bf[n] = *reinterpret_cast<const i32x4*>(base + boff[n]);
#pragma unroll
    for (int m = 0; m < 4; ++m)
      af[m] = *reinterpret_cast<const i32x4*>(base + aoff[m]);
    __builtin_amdgcn_s_setprio(1);
#pragma unroll
    for (int m = 0; m < 4; ++m)
#pragma unroll
      for (int n = 0; n < 4; ++n)
        acc[m][n] = __builtin_amdgcn_mfma_scale_f32_16x16x128_f8f6f4(
            up8(af[m]), up8(bf[n]), acc[m][n],
            4, 4, 0, 0x7F7F7F7Fu, 0, 0x7F7F7F7Fu);
    __builtin_amdgcn_s_setprio(0);
  };

  stage(0, a0, b0, b1, 0);
  asm volatile("s_waitcnt vmcnt(0)" ::: "memory");
  __builtin_amdgcn_s_barrier();

  for (int tap = 0; tap < 9; ++tap) {
#pragma unroll
    for (int j = 0; j < 4; ++j) {
      const int s = tap * 4 + j;
      if (j < 3) {
        stage((s + 1) & 1, a0, b0, b1, (j + 1) * 64);
      } else if (tap < 8) {
        const unsigned char* an = abase(tap + 1);
        stage((s + 1) & 1, an, b0 + TAPB4, b1 + TAPB4, 0);
        a0 = an;
      }
      compute(s & 1);
      asm volatile("s_waitcnt vmcnt(0)" ::: "memory");
      __builtin_amdgcn_s_barrier();
    }
    b0 += TAPB4; b1 += TAPB4;
  }
}

__device__ __forceinline__ void write_partials(
    f32x4 (&acc)[4][4], int* __restrict__ psum, long long* __restrict__ psq) {
  const int t = threadIdx.x;
  const int lane = t & 63;
  const int wid = t >> 6;
  const int wr = wid >> 2, wc = wid & 3;
  const int slot = blockIdx.x * 2 + wr;      // 0..1023
#pragma unroll
  for (int n = 0; n < 4; ++n) {
    int s1 = 0;
    long long s2 = 0;
#pragma unroll
    for (int m = 0; m < 4; ++m)
#pragma unroll
      for (int j = 0; j < 4; ++j) {
        int v = (int)acc[m][n][j];
        s1 += v;
        s2 += (long long)v * v;
      }
    s1 += __shfl_xor(s1, 16, 64);
    s1 += __shfl_xor(s1, 32, 64);
    s2 += __shfl_xor(s2, 16, 64);
    s2 += __shfl_xor(s2, 32, 64);
    if (lane < 16) {
      int c = wc * 64 + n * 16 + lane;
      psum[(size_t)c * 1024 + slot] = s1;
      psq[(size_t)c * 1024 + slot] = s2;
    }
  }
}

// ---------------- fused cooperative kernel ----------------
__global__ __launch_bounds__(512, 4) void conv_fused_kernel(
    const unsigned char* __restrict__ xb4,
    const unsigned char* __restrict__ wb4,
    const float* __restrict__ x,
    float* __restrict__ out,
    const unsigned char* __restrict__ zp,
    int* __restrict__ psum,
    long long* __restrict__ psq,
    const float* __restrict__ gamma,
    const float* __restrict__ beta,
    float* __restrict__ scale,
    float* __restrict__ shift) {
  cg::grid_group grid = cg::this_grid();
  __shared__ signed char lds[2][BUFB];
  f32x4 acc[4][4];
  conv_main(xb4, wb4, zp, lds, acc);
  write_partials(acc, psum, psq);

  __threadfence();
  grid.sync();

  const int t = threadIdx.x;
  const int lane = t & 63;
  const int wid = t >> 6;
  const int b = blockIdx.x;
  if (b < COUT && wid == 0) {
    const int co = b;
    const int* ps = psum + (size_t)co * 1024;
    const long long* pq = psq + (size_t)co * 1024;
    long long s1 = 0, s2 = 0;
#pragma unroll
    for (int i = 0; i < 16; ++i) {
      s1 += ps[lane * 16 + i];
      s2 += pq[lane * 16 + i];
    }
#pragma unroll
    for (int off = 32; off > 0; off >>= 1) {
      s1 += __shfl_xor(s1, off, 64);
      s2 += __shfl_xor(s2, off, 64);
    }
    if (lane == 0) {
      double cnt = (double)NPIX;
      double mean = (double)s1 / cnt;
      double ex2 = (double)s2 / cnt;
      double var = ex2 - mean * mean;
      double rs = 1.0 / sqrt(var + 1e-5);
      float g = gamma[co];
      scale[co] = (float)rs * g;
      shift[co] = beta[co] - (float)(mean * rs) * g;
    }
  }

  __threadfence();
  grid.sync();

  // normalize + residual + clip straight from registers (coalesced float4)
  const int wr = wid >> 2, wc = wid & 3;
  const int P0 = b * BM;
#pragma unroll
  for (int n = 0; n < 4; ++n) {
    int co = wc * 64 + n * 16 + (lane & 15);
    float sc = scale[co], sh = shift[co];
#pragma unroll
    for (int m = 0; m < 4; ++m) {
      int row = wr * 64 + m * 16 + ((lane >> 4) << 2);
      int P = P0 + row;
      int ni = P >> 10;
      int hw = P & 1023;
      const float* xr = x + (((size_t)ni * CIN + co) << 10) + hw;
      float4 r = *reinterpret_cast<const float4*>(xr);
      float4 o;
      o.x = fminf(1.f, fmaxf(-1.f, acc[m][n][0] * sc + sh + r.x));
      o.y = fminf(1.f, fmaxf(-1.f, acc[m][n][1] * sc + sh + r.y));
      o.z = fminf(1.f, fmaxf(-1.f, acc[m][n][2] * sc + sh + r.z));
      o.w = fminf(1.f, fmaxf(-1.f, acc[m][n][3] * sc + sh + r.w));
      *reinterpret_cast<float4*>(out + (((size_t)ni * COUT + co) << 10) + hw) = o;
    }
  }
}

// ---------------- split-path conv (r12-verified fallback) ----------------
__global__ __launch_bounds__(512, 4) void conv_kernel(
    const unsigned char* __restrict__ xb4,
    const unsigned char* __restrict__ wb4,
    short* __restrict__ cv,
    const unsigned char* __restrict__ zp,
    int* __restrict__ psum,
    long long* __restrict__ psq) {
  __shared__ signed char lds[2][BUFB];
  f32x4 acc[4][4];
  conv_main(xb4, wb4, zp, lds, acc);

  const int t = threadIdx.x;
  const int lane = t & 63;
  const int wid = t >> 6;
  const int wr = wid >> 2, wc = wid & 3;
  const int P0 = blockIdx.x * BM;
#pragma unroll
  for (int m = 0; m < 4; ++m) {
#pragma unroll
    for (int n = 0; n < 4; ++n) {
      int row = wr * 64 + m * 16 + ((lane >> 4) << 2);
      int co = wc * 64 + n * 16 + (lane & 15);
      int P = P0 + row;
      int ni = P >> 10;
      int hw = P & 1023;
      short4 v = make_short4((short)(int)acc[m][n][0], (short)(int)acc[m][n][1],
                             (short)(int)acc[m][n][2], (short)(int)acc[m][n][3]);
      *reinterpret_cast<short4*>(cv + (((size_t)ni * COUT + co) << 10) + hw) = v;
    }
  }
  write_partials(acc, psum, psq);
}

// ---------------- stats: 256 blocks, one channel each ----------------
__global__ __launch_bounds__(64) void stats_kernel(const int* __restrict__ psum,
                                                   const long long* __restrict__ psq,
                                                   const float* __restrict__ gamma,
                                                   const float* __restrict__ beta,
                                                   float* __restrict__ scale,
                                                   float* __restrict__ shift) {
  const int co = blockIdx.x;
  const int l = threadIdx.x;
  const int* ps = psum + (size_t)co * 1024;
  const long long* pq = psq + (size_t)co * 1024;
  long long s1 = 0, s2 = 0;
#pragma unroll
  for (int i = 0; i < 16; ++i) {
    s1 += ps[l * 16 + i];
    s2 += pq[l * 16 + i];
  }
#pragma unroll
  for (int off = 32; off > 0; off >>= 1) {
    s1 += __shfl_xor(s1, off, 64);
    s2 += __shfl_xor(s2, off, 64);
  }
  if (l == 0) {
    double cnt = (double)NPIX;
    double mean = (double)s1 / cnt;
    double ex2 = (double)s2 / cnt;
    double var = ex2 - mean * mean;
    double rs = 1.0 / sqrt(var + 1e-5);
    float g = gamma[co];
    scale[co] = (float)rs * g;
    shift[co] = beta[co] - (float)(mean * rs) * g;
  }
}

// ---------------- normalize + residual + clip (8 elems/thread) ----------------
__global__ __launch_bounds__(256) void final_kernel(const short* __restrict__ cv,
                                                    const float* __restrict__ x,
                                                    const float* __restrict__ scale,
                                                    const float* __restrict__ shift,
                                                    float* __restrict__ out) {
  size_t i = ((size_t)blockIdx.x * 256 + threadIdx.x) * 8;
  int co = (int)((i >> 10) & 255);
  size_t n = i >> 18;
  size_t hw = i & 1023;
  short4 c0 = *reinterpret_cast<const short4*>(cv + i);
  short4 c1 = *reinterpret_cast<const short4*>(cv + i + 4);
  const float* xr = x + ((n * CIN + co) << 10) + hw;
  float4 r0 = *reinterpret_cast<const float4*>(xr);
  float4 r1 = *reinterpret_cast<const float4*>(xr + 4);
  float sc = scale[co], sh = shift[co];
  float4 o0, o1;
  o0.x = fminf(1.f, fmaxf(-1.f, (float)c0.x * sc + sh + r0.x));
  o0.y = fminf(1.f, fmaxf(-1.f, (float)c0.y * sc + sh + r0.y));
  o0.z = fminf(1.f, fmaxf(-1.f, (float)c0.z * sc + sh + r0.z));
  o0.w = fminf(1.f, fmaxf(-1.f, (float)c0.w * sc + sh + r0.w));
  o1.x = fminf(1.f, fmaxf(-1.f, (float)c1.x * sc + sh + r1.x));
  o1.y = fminf(1.f, fmaxf(-1.f, (float)c1.y * sc + sh + r1.y));
  o1.z = fminf(1.f, fmaxf(-1.f, (float)c1.z * sc + sh + r1.z));
  o1.w = fminf(1.f, fmaxf(-1.f, (float)c1.w * sc + sh + r1.w));
  *reinterpret_cast<float4*>(out + i) = o0;
  *reinterpret_cast<float4*>(out + i + 4) = o1;
}

extern "C" void kernel_launch(void* const* d_in, const int* in_sizes, int n_in,
                              void* d_out, int out_size, void* d_ws, size_t ws_size,
                              hipStream_t stream) {
  const float* x     = (const float*)d_in[0];
  const float* W     = (const float*)d_in[1];
  const float* gamma = (const float*)d_in[2];
  const float* beta  = (const float*)d_in[3];
  float* out = (float*)d_out;
  char* ws = (char*)d_ws;

  unsigned char* xb4 = (unsigned char*)(ws + OFF_XB4);
  unsigned char* wb4 = (unsigned char*)(ws + OFF_WB4);
  short* cv = (short*)(ws + OFF_CONV);
  int* psum = (int*)(ws + OFF_PSUM);
  long long* psq = (long long*)(ws + OFF_PSQ);
  float* scale = (float*)(ws + OFF_SCALE);
  float* shift = (float*)(ws + OFF_SHIFT);
  unsigned char* zp = (unsigned char*)(ws + OFF_ZERO);

  pack_x4_kernel<<<NBATCH * HWDIM, 256, 0, stream>>>(x, xb4);
  pack_w4_kernel<<<577, 256, 0, stream>>>(W, (unsigned int*)wb4, (unsigned int*)zp);

  void* args[] = {&xb4, &wb4, &x, &out, &zp, &psum, &psq,
                  &gamma, &beta, &scale, &shift};
  hipError_t e = hipLaunchCooperativeKernel((const void*)conv_fused_kernel,
                                            dim3(NPIX / BM), dim3(512), args,
                                            0, stream);
  if (e != hipSuccess) {
    (void)hipGetLastError();   // clear error state; take the split path
    conv_kernel<<<NPIX / BM, 512, 0, stream>>>(xb4, wb4, cv, zp, psum, psq);
    stats_kernel<<<COUT, 64, 0, stream>>>(psum, psq, gamma, beta, scale, shift);
    final_kernel<<<(NBATCH * COUT * PIX_PER_IMG) / (256 * 8), 256, 0, stream>>>(
        cv, x, scale, shift, out);
  }
}

// Round 16
// 101.393 us; speedup vs baseline: 4.1149x; 4.1149x over previous
//
#include <hip/hip_runtime.h>

#define CIN   512
#define COUT  256
#define HWDIM 32
#define NBATCH 64
#define PIX_PER_IMG (HWDIM * HWDIM)          // 1024
#define NPIX (NBATCH * PIX_PER_IMG)          // 65536

typedef __attribute__((ext_vector_type(4))) int   i32x4;
typedef __attribute__((ext_vector_type(8))) int   i32x8;
typedef __attribute__((ext_vector_type(4))) float f32x4;

// ---------------- workspace layout ----------------
#define OFF_XB4   ((size_t)0)
#define OFF_WB4   ((size_t)16777216)
#define OFF_CONV  ((size_t)17367040)
#define OFF_PSUM  ((size_t)50921472)
#define OFF_PSQ   ((size_t)51970048)
#define OFF_SCALE ((size_t)54067200)
#define OFF_SHIFT (OFF_SCALE + 1024)
#define OFF_ZERO  (OFF_SHIFT + 1024)         // 1024 B zero page (fp4 0x00 = +0.0)

// fp4 e2m1: +1.0 = 0x2, -1.0 = 0xA
#define NIB(v) ((v) >= 0.f ? 0x2u : 0xAu)

// ---------------- pack x: f32 NCHW -> fp4 sign NHWC ----------------
__global__ __launch_bounds__(256) void pack_x4_kernel(const float* __restrict__ x,
                                                      unsigned char* __restrict__ xb4) {
  const int plane = blockIdx.x;            // n*32 + h, 2048 planes
  const int n = plane >> 5, h = plane & 31;
  __shared__ unsigned int tile[HWDIM * 66];   // [w][66] words of 8 ci-nibbles
  const int t = threadIdx.x;
  const float* xp = x + (size_t)n * CIN * PIX_PER_IMG + (size_t)h * HWDIM;
#pragma unroll
  for (int it = 0; it < 2; ++it) {
    int idx = it * 256 + t;                // 0..511
    int cib = idx >> 3;                    // 8-ci group 0..63
    int w4 = (idx & 7) << 2;               // 0,4,..,28
    unsigned n0 = 0, n1 = 0, n2 = 0, n3 = 0;
#pragma unroll
    for (int d = 0; d < 8; ++d) {
      float4 f = *reinterpret_cast<const float4*>(
          xp + (size_t)(cib * 8 + d) * PIX_PER_IMG + w4);
      n0 |= NIB(f.x) << (4 * d);
      n1 |= NIB(f.y) << (4 * d);
      n2 |= NIB(f.z) << (4 * d);
      n3 |= NIB(f.w) << (4 * d);
    }
    tile[(w4 + 0) * 66 + cib] = n0;
    tile[(w4 + 1) * 66 + cib] = n1;
    tile[(w4 + 2) * 66 + cib] = n2;
    tile[(w4 + 3) * 66 + cib] = n3;
  }
  __syncthreads();
  uint4* xo = reinterpret_cast<uint4*>(xb4 + (size_t)plane * (HWDIM * CIN / 2));
#pragma unroll
  for (int it = 0; it < 2; ++it) {
    int cc = it * 256 + t;                 // 16B chunk 0..511
    int w = cc >> 4, c4 = (cc & 15) << 2;
    uint4 v = make_uint4(tile[w * 66 + c4], tile[w * 66 + c4 + 1],
                         tile[w * 66 + c4 + 2], tile[w * 66 + c4 + 3]);
    xo[cc] = v;
  }
}

// ---------------- pack W -> fp4 [tap][co][ci/2]; block 576 writes zero page ----
__global__ __launch_bounds__(256) void pack_w4_kernel(const float* __restrict__ W,
                                                      unsigned int* __restrict__ wb4,
                                                      unsigned int* __restrict__ zpw) {
  if (blockIdx.x == 576) {                  // 1 KB zero page for halo reads
    zpw[threadIdx.x] = 0u;
    return;
  }
  int idxu = blockIdx.x * 256 + threadIdx.x;    // u32 id, 9*256*64 = 147456 total
  int tap = idxu / (COUT * 64);
  int rem = idxu - tap * (COUT * 64);
  int co = rem >> 6;
  int ci0 = (rem & 63) << 3;
  unsigned nib = 0;
#pragma unroll
  for (int d = 0; d < 8; ++d) {
    float v = W[((size_t)co * CIN + ci0 + d) * 9 + tap];
    nib |= NIB(v) << (4 * d);
  }
  wb4[idxu] = nib;                          // layout [tap][co][64 words]
}

// ---------------- conv: MX-fp4 MFMA GEMM, BM=128, ring-2, 2 blocks/CU ----------
#define BM 128
#define BKB 64                       // bytes per row per step (= 128 fp4 elems)
#define ABYTES (BM * BKB)            // 8192
#define BUFB   (ABYTES + COUT * BKB) // 24576
#define TAPB4 (COUT * (CIN / 2))     // 65536 B per tap of wb4

__device__ __forceinline__ void load16(const void* g, void* l) {
  __builtin_amdgcn_global_load_lds((const __attribute__((address_space(1))) void*)g,
                                   (__attribute__((address_space(3))) void*)l, 16, 0, 0);
}

__device__ __forceinline__ i32x8 up8(i32x4 v) {
  i32x8 r;
  r[0] = v[0]; r[1] = v[1]; r[2] = v[2]; r[3] = v[3];
  r[4] = 0;    r[5] = 0;    r[6] = 0;    r[7] = 0;
  return r;
}

__global__ __launch_bounds__(512, 4) void conv_kernel(
    const unsigned char* __restrict__ xb4,   // [65536][256]
    const unsigned char* __restrict__ wb4,   // [9][256][256]
    short* __restrict__ cv,                  // [64][256][1024]
    const unsigned char* __restrict__ zp,
    int* __restrict__ psum,                  // [256][1024] channel-major partials
    long long* __restrict__ psq) {
  __shared__ signed char lds[2][BUFB];       // 48 KB -> 2 blocks/CU
  const int t = threadIdx.x;
  const int wid = t >> 6, lane = t & 63;
  const int b = blockIdx.x;                  // 0..511
  const int nimg = b >> 3;
  const int h0 = (b & 7) * 4;                // 4 image rows per block

  const int wr = wid >> 2;                   // 0..1 (M, 64 rows each)
  const int wc = wid & 3;                    // 0..3 (N, 64 cols each)

  f32x4 acc[4][4];
#pragma unroll
  for (int m = 0; m < 4; ++m)
#pragma unroll
    for (int n = 0; n < 4; ++n) { f32x4 z = {0.f, 0.f, 0.f, 0.f}; acc[m][n] = z; }

  // A chunk c = t: row r = t>>2 (0..127), slot = t&3; source pre-swizzled
  auto abase = [&](int tap) -> const unsigned char* {
    int r = t >> 2;
    int sw = ((t & 3) ^ ((t >> 3) & 3)) << 4;
    int dh = tap / 3 - 1, dw = tap % 3 - 1;
    int hs = h0 + (r >> 5) + dh;
    int ws2 = (r & 31) + dw;
    bool ok = ((unsigned)hs < 32u) && ((unsigned)ws2 < 32u);
    return ok ? xb4 + (size_t)((nimg * 32 + hs) * 32 + ws2) * 256 + sw
              : zp + sw;
  };
  // B chunks c = t, 512+t: co = c>>2, same swizzle
  auto bbase = [&](int c) -> const unsigned char* {
    int co = c >> 2;
    int sw = ((c & 3) ^ ((c >> 3) & 3)) << 4;
    return wb4 + (size_t)co * 256 + sw;      // tap 0; advance by TAPB4 per tap
  };

  const unsigned char* a0 = abase(0);
  const unsigned char* b0 = bbase(t);
  const unsigned char* b1 = bbase(512 + t);

  // read-side frag offsets (verified 0-conflict swizzle; 64-B rows)
  const int koff = (lane >> 4) << 4;
  const int ksw  = (((lane >> 1) & 3) << 4);
  int aoff[4], boff[4];
#pragma unroll
  for (int m = 0; m < 4; ++m) {
    int row = wr * 64 + m * 16 + (lane & 15);
    aoff[m] = row * BKB + (koff ^ ksw);
  }
#pragma unroll
  for (int n = 0; n < 4; ++n) {
    int col = wc * 64 + n * 16 + (lane & 15);
    boff[n] = ABYTES + col * BKB + (koff ^ ksw);
  }

  auto stage = [&](int buf, const unsigned char* A0, const unsigned char* B0,
                   const unsigned char* B1, int off) {
    signed char* dst = &lds[buf][0];
    load16(A0 + off, (void*)(dst + t * 16));
    load16(B0 + off, (void*)(dst + ABYTES + t * 16));
    load16(B1 + off, (void*)(dst + ABYTES + (512 + t) * 16));
  };

  auto compute = [&](int buf) {
    const signed char* base = &lds[buf][0];
    i32x4 af[4], bf[4];
#pragma unroll
    for (int n = 0; n < 4; ++n)
      bf[n] = *reinterpret_cast<const i32x4*>(base + boff[n]);
#pragma unroll
    for (int m = 0; m < 4; ++m)
      af[m] = *reinterpret_cast<const i32x4*>(base + aoff[m]);
    __builtin_amdgcn_s_setprio(1);
#pragma unroll
    for (int m = 0; m < 4; ++m)
#pragma unroll
      for (int n = 0; n < 4; ++n)
        acc[m][n] = __builtin_amdgcn_mfma_scale_f32_16x16x128_f8f6f4(
            up8(af[m]), up8(bf[n]), acc[m][n],
            4, 4,                  // cbsz=fp4, blgp=fp4
            0, 0x7F7F7F7Fu,        // opselA, scaleA = 1.0 (e8m0 127)
            0, 0x7F7F7F7Fu);       // opselB, scaleB
    __builtin_amdgcn_s_setprio(0);
  };

  // prologue: stage step 0 into buf 0
  stage(0, a0, b0, b1, 0);
  asm volatile("s_waitcnt vmcnt(0)" ::: "memory");
  __builtin_amdgcn_s_barrier();

  for (int tap = 0; tap < 9; ++tap) {
#pragma unroll
    for (int j = 0; j < 4; ++j) {
      const int s = tap * 4 + j;
      // issue next step's 3 loads early (ring-2; prior barrier made buf free)
      if (j < 3) {
        stage((s + 1) & 1, a0, b0, b1, (j + 1) * 64);
      } else if (tap < 8) {
        const unsigned char* an = abase(tap + 1);
        stage((s + 1) & 1, an, b0 + TAPB4, b1 + TAPB4, 0);
        a0 = an;
      }
      compute(s & 1);                        // ds_read+MFMA cover the loads
      asm volatile("s_waitcnt vmcnt(0)" ::: "memory");
      __builtin_amdgcn_s_barrier();          // single barrier per step
    }
    b0 += TAPB4; b1 += TAPB4;
  }

  // epilogue A: int16 conv output, NCHW (acc floats are exact integers)
  const int P0 = b * BM;
#pragma unroll
  for (int m = 0; m < 4; ++m) {
#pragma unroll
    for (int n = 0; n < 4; ++n) {
      int row = wr * 64 + m * 16 + ((lane >> 4) << 2);
      int co = wc * 64 + n * 16 + (lane & 15);
      int P = P0 + row;
      int ni = P >> 10;
      int hw = P & 1023;
      short4 v = make_short4((short)(int)acc[m][n][0], (short)(int)acc[m][n][1],
                             (short)(int)acc[m][n][2], (short)(int)acc[m][n][3]);
      *reinterpret_cast<short4*>(cv + (((size_t)ni * COUT + co) << 10) + hw) = v;
    }
  }

  // epilogue B: per-channel partials, channel-major, non-atomic
  const int slot = b * 2 + wr;               // 0..1023
#pragma unroll
  for (int n = 0; n < 4; ++n) {
    int s1 = 0;
    long long s2 = 0;
#pragma unroll
    for (int m = 0; m < 4; ++m)
#pragma unroll
      for (int j = 0; j < 4; ++j) {
        int v = (int)acc[m][n][j];
        s1 += v;
        s2 += (long long)v * v;
      }
    s1 += __shfl_xor(s1, 16, 64);
    s1 += __shfl_xor(s1, 32, 64);
    s2 += __shfl_xor(s2, 16, 64);
    s2 += __shfl_xor(s2, 32, 64);
    if (lane < 16) {
      int c = wc * 64 + n * 16 + lane;
      psum[(size_t)c * 1024 + slot] = s1;
      psq[(size_t)c * 1024 + slot] = s2;
    }
  }
}

// ---------------- stats: 256 blocks, one channel each ----------------
__global__ __launch_bounds__(64) void stats_kernel(const int* __restrict__ psum,
                                                   const long long* __restrict__ psq,
                                                   const float* __restrict__ gamma,
                                                   const float* __restrict__ beta,
                                                   float* __restrict__ scale,
                                                   float* __restrict__ shift) {
  const int co = blockIdx.x;
  const int l = threadIdx.x;
  const int* ps = psum + (size_t)co * 1024;
  const long long* pq = psq + (size_t)co * 1024;
  long long s1 = 0, s2 = 0;
#pragma unroll
  for (int i = 0; i < 16; ++i) {
    s1 += ps[l * 16 + i];
    s2 += pq[l * 16 + i];
  }
#pragma unroll
  for (int off = 32; off > 0; off >>= 1) {
    s1 += __shfl_xor(s1, off, 64);
    s2 += __shfl_xor(s2, off, 64);
  }
  if (l == 0) {
    double cnt = (double)NPIX;
    double mean = (double)s1 / cnt;
    double ex2 = (double)s2 / cnt;
    double var = ex2 - mean * mean;
    double rs = 1.0 / sqrt(var + 1e-5);
    float g = gamma[co];
    scale[co] = (float)rs * g;
    shift[co] = beta[co] - (float)(mean * rs) * g;
  }
}

// ---------------- normalize + residual + clip (8 elems/thread) ----------------
__global__ __launch_bounds__(256) void final_kernel(const short* __restrict__ cv,
                                                    const float* __restrict__ x,
                                                    const float* __restrict__ scale,
                                                    const float* __restrict__ shift,
                                                    float* __restrict__ out) {
  size_t i = ((size_t)blockIdx.x * 256 + threadIdx.x) * 8;
  int co = (int)((i >> 10) & 255);
  size_t n = i >> 18;
  size_t hw = i & 1023;
  short4 c0 = *reinterpret_cast<const short4*>(cv + i);
  short4 c1 = *reinterpret_cast<const short4*>(cv + i + 4);
  const float* xr = x + ((n * CIN + co) << 10) + hw;
  float4 r0 = *reinterpret_cast<const float4*>(xr);
  float4 r1 = *reinterpret_cast<const float4*>(xr + 4);
  float sc = scale[co], sh = shift[co];
  float4 o0, o1;
  o0.x = fminf(1.f, fmaxf(-1.f, (float)c0.x * sc + sh + r0.x));
  o0.y = fminf(1.f, fmaxf(-1.f, (float)c0.y * sc + sh + r0.y));
  o0.z = fminf(1.f, fmaxf(-1.f, (float)c0.z * sc + sh + r0.z));
  o0.w = fminf(1.f, fmaxf(-1.f, (float)c0.w * sc + sh + r0.w));
  o1.x = fminf(1.f, fmaxf(-1.f, (float)c1.x * sc + sh + r1.x));
  o1.y = fminf(1.f, fmaxf(-1.f, (float)c1.y * sc + sh + r1.y));
  o1.z = fminf(1.f, fmaxf(-1.f, (float)c1.z * sc + sh + r1.z));
  o1.w = fminf(1.f, fmaxf(-1.f, (float)c1.w * sc + sh + r1.w));
  *reinterpret_cast<float4*>(out + i) = o0;
  *reinterpret_cast<float4*>(out + i + 4) = o1;
}

extern "C" void kernel_launch(void* const* d_in, const int* in_sizes, int n_in,
                              void* d_out, int out_size, void* d_ws, size_t ws_size,
                              hipStream_t stream) {
  const float* x     = (const float*)d_in[0];
  const float* W     = (const float*)d_in[1];
  const float* gamma = (const float*)d_in[2];
  const float* beta  = (const float*)d_in[3];
  float* out = (float*)d_out;
  char* ws = (char*)d_ws;

  unsigned char* xb4 = (unsigned char*)(ws + OFF_XB4);
  unsigned char* wb4 = (unsigned char*)(ws + OFF_WB4);
  short* cv = (short*)(ws + OFF_CONV);
  int* psum = (int*)(ws + OFF_PSUM);
  long long* psq = (long long*)(ws + OFF_PSQ);
  float* scale = (float*)(ws + OFF_SCALE);
  float* shift = (float*)(ws + OFF_SHIFT);
  unsigned char* zp = (unsigned char*)(ws + OFF_ZERO);

  pack_x4_kernel<<<NBATCH * HWDIM, 256, 0, stream>>>(x, xb4);
  pack_w4_kernel<<<577, 256, 0, stream>>>(W, (unsigned int*)wb4, (unsigned int*)zp);
  conv_kernel<<<NPIX / BM, 512, 0, stream>>>(xb4, wb4, cv, zp, psum, psq);
  stats_kernel<<<COUT, 64, 0, stream>>>(psum, psq, gamma, beta, scale, shift);
  final_kernel<<<(NBATCH * COUT * PIX_PER_IMG) / (256 * 8), 256, 0, stream>>>(
      cv, x, scale, shift, out);
}